// Round 5
// baseline (8060.474 us; speedup 1.0000x reference)
//
#include <hip/hip_runtime.h>
#include <hip/hip_bf16.h>

// Hypernetwork RNN scan. B=16, N=2048, M=H=64, L*E=1024, Cout=256.
// Round 5: single-atomic tagged-u64 m exchange (tag+payload in one relaxed
// 64-bit LLC atomic; ping-pong parity slots; no flag RTT, no second payload
// RTT), register-resident Wd (16 uint4/thread; LDS-port floor removed),
// merged B+C phase on wave 0 (2 syncthreads/step).
//   K1 cvt:    Wd -> bf16 slice layout; dec_w -> bf16 lane-packed (loss)
//   K2 build_T, K3 build_P: unchanged precompute (8 MB + 16 MB)
//   K4 recur:  64 WGs = 16 batches x 4 i-slices
//   K5 loss:   parallel logits/LSE/NLL over the m history

typedef unsigned int uint_t;
typedef unsigned short us_t;
typedef unsigned long long u64_t;

__device__ __forceinline__ us_t f2bf(float f) {
    uint_t u = __float_as_uint(f);
    uint_t r = u + 0x7fffu + ((u >> 16) & 1u);   // RNE
    return (us_t)(r >> 16);
}
__device__ __forceinline__ float bf2f(us_t s) {
    return __uint_as_float(((uint_t)s) << 16);
}
__device__ __forceinline__ float bflo(uint_t u) { return __uint_as_float(u << 16); }
__device__ __forceinline__ float bfhi(uint_t u) { return __uint_as_float(u & 0xffff0000u); }

#define MAC8(q, acc)                                                    \
    acc += bflo(q.x) * mreg[0] + bfhi(q.x) * mreg[1]                    \
         + bflo(q.y) * mreg[2] + bfhi(q.y) * mreg[3]                    \
         + bflo(q.z) * mreg[4] + bfhi(q.z) * mreg[5]                    \
         + bflo(q.w) * mreg[6] + bfhi(q.w) * mreg[7];

#define LOADM8(jp)                                                      \
    float4 _ml = m4[(jp) * 2], _mh = m4[(jp) * 2 + 1];                  \
    float mreg[8] = {_ml.x, _ml.y, _ml.z, _ml.w, _mh.x, _mh.y, _mh.z, _mh.w};

// ---------------- K1: convert/swizzle weights ----------------
// WdG us-layout [s<4][jp<8][o<1024][k<8], o = h*16+il,
//   value = Wd[h][(s*16+il)*64 + jp*8+k]  (uint4 at jp*1024+o is lane-contig).
// decwY us-layout [mm<64][lane<64][k<4], value = decw[mm*256 + k*64 + lane].
__global__ void cvt_kernel(const float* __restrict__ Wdecw,
                           const float* __restrict__ decw,
                           us_t* __restrict__ WdG, us_t* __restrict__ decwY) {
    int o = blockIdx.x * 256 + threadIdx.x;
    if (o < 262144) {
        int s = o >> 16;
        int idx = o & 65535;
        int k = idx & 7;
        int oo = (idx >> 3) & 1023;
        int jp = idx >> 13;
        int h = oo >> 4, il = oo & 15;
        int i = s * 16 + il;
        int j = jp * 8 + k;
        WdG[o] = f2bf(Wdecw[h * 4096 + i * 64 + j]);
    } else {
        int oo = o - 262144;
        if (oo < 16384) {
            int k = oo & 3, lane = (oo >> 2) & 63, mm = oo >> 8;
            decwY[oo] = f2bf(decw[mm * 256 + k * 64 + lane]);
        }
    }
}

// ---------------- K2: token contribution table ----------------
__global__ void build_T(const float* __restrict__ emb, const float* __restrict__ Wencw,
                        const float* __restrict__ bencw, float* __restrict__ T) {
    int l = blockIdx.x >> 8, v = blockIdx.x & 255, h2 = threadIdx.x;  // h2 < 128
    float acc = 0.f;
#pragma unroll
    for (int e = 0; e < 16; ++e) {
        int d = 64 + l * 16 + e;
        float w = (h2 < 64) ? Wencw[d * 64 + h2] : bencw[d * 64 + (h2 - 64)];
        acc += emb[v * 16 + e] * w;
    }
    T[blockIdx.x * 128 + h2] = acc;
}

// ---------------- K3: window precompute P ----------------
__global__ void build_P(const float* __restrict__ T, const int* __restrict__ x0,
                        const float* __restrict__ Wencb, const float* __restrict__ bencb,
                        float* __restrict__ P) {
    int t = blockIdx.x >> 4, b = blockIdx.x & 15, h2 = threadIdx.x;  // h2 < 128
    float acc = (h2 < 64) ? Wencb[h2] : bencb[h2 - 64];
    for (int l = 0; l < 64; ++l) {
        int p = t + l;
        int v = (p < 64) ? 0 : x0[b * 2048 + (p - 64)];
        acc += T[(l * 256 + v) * 128 + h2];
    }
    P[blockIdx.x * 128 + h2] = acc;
}

// ---------------- K4: sequential recurrence ----------------
// grid 64: b = blk&15, s = blk>>4. LDS ~27 KB static; VGPR-resident Wd, so
// __launch_bounds__(512, 2) lifts the VGPR cap to 256 (1 WG/CU regardless).
__global__ __launch_bounds__(512, 2) void recur(
    const float* __restrict__ Wencw, const float* __restrict__ bencw,
    const float* __restrict__ bdecw, const float* __restrict__ bdecb,
    const float* __restrict__ Wdecb, const us_t* __restrict__ WdG,
    const float* __restrict__ P, float* __restrict__ mh,
    u64_t* __restrict__ mx) {
    const int b = blockIdx.x & 15, s = blockIdx.x >> 4;
    const int tid = threadIdx.x;

    __shared__ __align__(16) us_t EWm2[8192];     // [jp][h2][8] bf16
    __shared__ us_t  wdbt_s[64 * 17];             // [j][il]  W_dec_b[i*64+j]
    __shared__ us_t  bdec_s[64 * 17];             // [h][il]  b_dec_w[h][i]
    __shared__ float hw_s[64], hb_s[64];
    __shared__ __align__(16) float m_s[64];
    __shared__ float V_s[64 * 17];                // [h][il] stride-17
    __shared__ float bias_s[16];
    __shared__ us_t  nmb_s[16];

    // ---- init: Wd slice -> registers (rows o=tid and o=tid+512) ----
    uint4 wreg[16];
    {
        const uint4* g4 = (const uint4*)WdG + s * 8192;
#pragma unroll
        for (int jp = 0; jp < 8; ++jp) {
            wreg[jp]     = g4[jp * 1024 + tid];
            wreg[8 + jp] = g4[jp * 1024 + tid + 512];
        }
    }
    for (int k = tid; k < 8192; k += 512) {
        int kk = k & 7, h2 = (k >> 3) & 127, jp = k >> 10;
        int j = jp * 8 + kk;
        float v = (h2 < 64) ? Wencw[j * 64 + h2] : bencw[j * 64 + (h2 - 64)];
        EWm2[k] = f2bf(v);
    }
    for (int k = tid; k < 1024; k += 512) {
        int j = k >> 4, il = k & 15;
        wdbt_s[j * 17 + il] = f2bf(Wdecb[(s * 16 + il) * 64 + j]);
        bdec_s[j * 17 + il] = f2bf(bdecw[j * 64 + s * 16 + il]);
    }
    if (tid < 16) bias_s[tid] = bdecb[s * 16 + tid];
    if (tid < 64) m_s[tid] = 0.f;
    __syncthreads();

    // encoder m-rows -> registers (henc threads only)
    uint4 ereg[8];
    if (tid < 128) {
        const uint4* e4 = (const uint4*)EWm2;
#pragma unroll
        for (int jp = 0; jp < 8; ++jp) ereg[jp] = e4[jp * 128 + tid];
    }

    float preg = 0.f;
    if (tid < 128) preg = P[b * 128 + tid];  // t = 0

    const int hA = tid >> 4, ilA = tid & 15;
    const float4* m4 = (const float4*)m_s;

    for (int t = 0; t < 2048; ++t) {
        // ---- phase A: prefetch P(t+1); V slice from wreg; henc from ereg ----
        float pnext = 0.f;
        int tp = (t < 2047) ? (t + 1) : 2047;
        if (tid < 128) pnext = P[(tp * 16 + b) * 128 + tid];

        float a0 = 0.f, a1 = 0.f;
        if (tid < 128) {
            float ae = preg;
#pragma unroll
            for (int jp = 0; jp < 8; ++jp) {
                LOADM8(jp);
                uint4 q0 = wreg[jp], q1 = wreg[8 + jp], e = ereg[jp];
                MAC8(q0, a0);
                MAC8(q1, a1);
                MAC8(e, ae);
            }
            float sg = 1.f / (1.f + __expf(-ae));
            if (tid < 64) hw_s[tid] = sg; else hb_s[tid - 64] = sg;
        } else {
#pragma unroll
            for (int jp = 0; jp < 8; ++jp) {
                LOADM8(jp);
                uint4 q0 = wreg[jp], q1 = wreg[8 + jp];
                MAC8(q0, a0);
                MAC8(q1, a1);
            }
        }
        V_s[hA * 17 + ilA] = a0;
        V_s[(hA + 32) * 17 + ilA] = a1;
        preg = pnext;
        __syncthreads();

        // ---- wave 0: r + sigmoid, publish tagged u64s, poll peers ----
        if (tid < 64) {
            if (tid < 16) {
                float r = bias_s[tid];
#pragma unroll
                for (int h = 0; h < 64; ++h) r += hw_s[h] * V_s[h * 17 + tid];
#pragma unroll
                for (int h = 0; h < 64; ++h) r += hb_s[h] * bf2f(bdec_s[h * 17 + tid]);
#pragma unroll
                for (int j = 0; j < 64; ++j) r += m_s[j] * bf2f(wdbt_s[j * 17 + tid]);
                float nm = 1.f / (1.f + __expf(-r));
                us_t nb = f2bf(nm);           // bf16-round: all WGs agree exactly
                nmb_s[tid] = nb;
                m_s[s * 16 + tid] = bf2f(nb); // own slice, local
            }
            __builtin_amdgcn_s_waitcnt(0xC07F);  // lgkmcnt(0): nmb_s in-wave vis
            if (tid < 8) {
                u64_t v = ((u64_t)(uint_t)(t + 1) << 32)
                        | (uint_t)nmb_s[2 * tid]
                        | ((uint_t)nmb_s[2 * tid + 1] << 16);
                __hip_atomic_store(&mx[(u64_t)(((t & 1) * 64 + b * 4 + s) * 16 + tid)],
                                   v, __ATOMIC_RELAXED, __HIP_MEMORY_SCOPE_AGENT);
            }
            if (tid < 24) {
                int pi = tid >> 3;
                int peer = pi + (pi >= s ? 1 : 0);
                int k = tid & 7;
                const u64_t* slot = &mx[(u64_t)(((t & 1) * 64 + b * 4 + peer) * 16 + k)];
                const uint_t tg = (uint_t)(t + 1);
                u64_t v;
                for (;;) {
                    v = __hip_atomic_load(slot, __ATOMIC_RELAXED,
                                          __HIP_MEMORY_SCOPE_AGENT);
                    if (__ballot((uint_t)(v >> 32) == tg) == 0xFFFFFFull) break;
                    __builtin_amdgcn_s_sleep(1);
                }
                m_s[peer * 16 + 2 * k]     = bf2f((us_t)(v & 0xFFFFu));
                m_s[peer * 16 + 2 * k + 1] = bf2f((us_t)((v >> 16) & 0xFFFFu));
            }
            __builtin_amdgcn_s_waitcnt(0xC07F);  // m_s stores visible in-wave
            if (s == 0) mh[(t * 16 + b) * 64 + tid] = m_s[tid];  // history for loss
        }
        __syncthreads();
    }
}

// ---------------- K5: parallel loss ----------------
__global__ __launch_bounds__(256) void loss_kernel(
    const float* __restrict__ mh, const us_t* __restrict__ decwY,
    const float* __restrict__ decb, const int* __restrict__ x0,
    float* __restrict__ out) {
    __shared__ __align__(16) us_t dw[16384];   // [mm][lane][k<4] bf16
    const int tid = threadIdx.x;
    {
        const uint4* g4 = (const uint4*)decwY;
        uint4* l4 = (uint4*)dw;
        for (int k = tid; k < 2048; k += 256) l4[k] = g4[k];
    }
    __syncthreads();
    const int lane = tid & 63, wv = tid >> 6;
    const uint2* dwu2 = (const uint2*)dw;
    float b0 = decb[lane], b1 = decb[lane + 64];
    float b2 = decb[lane + 128], b3 = decb[lane + 192];
    for (int r = 0; r < 8; ++r) {
        int row = blockIdx.x * 32 + wv * 8 + r;
        float mL = mh[row * 64 + lane];
        float l0 = b0, l1 = b1, l2 = b2, l3 = b3;
#pragma unroll
        for (int mm = 0; mm < 64; ++mm) {
            float mv = __shfl(mL, mm, 64);
            uint2 q = dwu2[mm * 64 + lane];
            l0 += mv * bflo(q.x);
            l1 += mv * bfhi(q.x);
            l2 += mv * bflo(q.y);
            l3 += mv * bfhi(q.y);
        }
        float mx = fmaxf(fmaxf(l0, l1), fmaxf(l2, l3));
#pragma unroll
        for (int o = 32; o > 0; o >>= 1) mx = fmaxf(mx, __shfl_xor(mx, o, 64));
        float se = __expf(l0 - mx) + __expf(l1 - mx) + __expf(l2 - mx) + __expf(l3 - mx);
#pragma unroll
        for (int o = 32; o > 0; o >>= 1) se += __shfl_xor(se, o, 64);
        float lse = mx + __logf(se);
        int t = row >> 4, bb = row & 15;
        int y = x0[bb * 2048 + t];
        int hi = y >> 6;
        float cand = hi == 0 ? l0 : (hi == 1 ? l1 : (hi == 2 ? l2 : l3));
        float ly = __shfl(cand, y & 63, 64);
        if (lane == 0) out[row] = (lse - ly) * 1.4426950408889634f;
    }
}

extern "C" void kernel_launch(void* const* d_in, const int* in_sizes, int n_in,
                              void* d_out, int out_size, void* d_ws, size_t ws_size,
                              hipStream_t stream) {
    const int*   x0    = (const int*)d_in[0];
    const float* emb   = (const float*)d_in[1];
    const float* Wencw = (const float*)d_in[2];
    const float* Wencb = (const float*)d_in[3];
    const float* Wdecw = (const float*)d_in[4];
    const float* Wdecb = (const float*)d_in[5];
    const float* bencw = (const float*)d_in[6];
    const float* bencb = (const float*)d_in[7];
    const float* bdecw = (const float*)d_in[8];
    const float* bdecb = (const float*)d_in[9];
    const float* decw  = (const float*)d_in[10];
    const float* decb  = (const float*)d_in[11];
    float* out = (float*)d_out;

    char* ws = (char*)d_ws;
    us_t*  WdG   = (us_t*)(ws);                 //       0 .. 524288
    us_t*  decwY = (us_t*)(ws + 524288);        //  524288 .. 557056
    u64_t* mx    = (u64_t*)(ws + 557056);       //  557056 .. 573440 (16 KB)
    float* T     = (float*)(ws + 573440);       //  573440 .. 8962048 (8 MB)
    float* mh    = T;                           //  alias: T dead after build_P
    float* P     = (float*)(ws + 8962048);      // 8962048 .. 25739264 (16 MB)

    hipMemsetAsync(mx, 0, 16384, stream);
    cvt_kernel<<<1088, 256, 0, stream>>>(Wdecw, decw, WdG, decwY);
    build_T<<<16384, 128, 0, stream>>>(emb, Wencw, bencw, T);
    build_P<<<32768, 128, 0, stream>>>(T, x0, Wencb, bencb, P);
    recur<<<64, 512, 0, stream>>>(Wencw, bencw, bdecw, bdecb, Wdecb,
                                  WdG, P, mh, mx);
    loss_kernel<<<1024, 256, 0, stream>>>(mh, decwY, decb, x0, out);
}